// Round 9
// baseline (212.945 us; speedup 1.0000x reference)
//
#include <hip/hip_runtime.h>
#include <hip/hip_bf16.h>
#include <hip/hip_cooperative_groups.h>

#define BATCH 16
#define C 768
#define T 8
#define R 64
#define HW 4096
#define NPS (HW*C)   // 3145728 elements per sample
#define GN_EPS 1e-5f

typedef short bf16x8 __attribute__((ext_vector_type(8)));
typedef float f32x4 __attribute__((ext_vector_type(4)));

static __device__ __forceinline__ unsigned short f2bf(float f) {
    __hip_bfloat16 h = __float2bfloat16(f);
    return *reinterpret_cast<unsigned short*>(&h);
}

// ================= single cooperative kernel =================
// 256 blocks (1/CU), 512 threads = 8 waves (2/SIMD). Block = (sample b, chunk of 256 rows).
// Phase 1: stats over OWN chunk (warms L3 with exactly the data this block re-reads),
//          weight fragments fp32->bf16 into registers (gamma folded), u/w fold dots.
// grid.sync()
// Phase 2: waves 0-3 produce GEMM1+gelu -> hsb[i&1]; waves 4-7 consume GEMM2+residual
//          with nontemporal stores. TWO barriers/iter:
//          #A after vmcnt = data-ready (vmcnt is PER-WAVE; each wave stages only 4 of
//          16 rows, so cross-wave completion needs the barrier — round-8 race fix),
//          #B after h-publish = safe to overwrite buffer (i+2)%3 == (i-1)%3.
__global__ __launch_bounds__(512, 1) void fused_all(
        const float* __restrict__ x, const int* __restrict__ task_ids,
        const float* __restrict__ gamma, const float* __restrict__ beta,
        const float* __restrict__ Wdn, const float* __restrict__ Wup,
        const float* __restrict__ scales,
        float* __restrict__ partials, float* __restrict__ out) {
    __shared__ char xsb[3 * 49152];            // 144 KiB: 3 x (16 rows x 3072 B)
    __shared__ char hsb[2][2048];              // double-buffered bf16 h (16 x 64)
    __shared__ float uws[4][16][2];            // per producer-wave u/w per R-row
    __shared__ float red[8][2];                // per-wave stats partials

    int bid = blockIdx.x;
    int b = bid >> 4;
    int chunk = bid & 15;
    int tid = threadIdx.x;
    int wvid = tid >> 6, lane = tid & 63;
    int lr = lane & 15, lg = lane >> 4;
    int swz = (lr & 7) << 4;

    int t = task_ids[b];
    float sc = scales[t];

    size_t basee = (size_t)b * NPS + (size_t)chunk * 256 * C;   // elements
    const float4* xp4 = (const float4*)(x + basee);
    const char* xbase_c = (const char*)(x + basee);
    float* outp = out + basee;

    // ---------- phase 1a: stats over own chunk (49152 float4 / 512 thr = 96 each) ----------
    {
        float s = 0.f, q = 0.f;
        #pragma unroll 16
        for (int i = 0; i < 96; i++) {
            float4 v = xp4[i * 512 + tid];
            s += v.x + v.y + v.z + v.w;
            q += v.x*v.x + v.y*v.y + v.z*v.z + v.w*v.w;
        }
        for (int off = 32; off > 0; off >>= 1) {
            s += __shfl_down(s, off);
            q += __shfl_down(q, off);
        }
        if (lane == 0) { red[wvid][0] = s; red[wvid][1] = q; }
    }

#define STAGE(ldbuf, tileidx) do {                                               \
    const char* _gs = xbase_c + (size_t)(tileidx) * 49152;                       \
    char* _ld = (ldbuf);                                                         \
    _Pragma("unroll")                                                            \
    for (int _jj = 0; _jj < 12; _jj++) {                                         \
        int _j = pw * 12 + _jj;                                                  \
        int _row = _j / 3;                                                       \
        int _sub = _j - _row * 3;                                                \
        int _cb = (_sub * 1024 + lane * 16) ^ ((_row & 7) << 4);                 \
        __builtin_amdgcn_global_load_lds(                                        \
            (const __attribute__((address_space(1))) void*)(_gs + _row * 3072 + _cb), \
            (__attribute__((address_space(3))) void*)(_ld + (size_t)_j * 1024),  \
            16, 0, 0);                                                           \
    }                                                                            \
} while (0)

    if (wvid < 4) {
        // ======================= PRODUCER (waves 0-3) =======================
        int pw = wvid;

        // phase 1b: a1 frags fp32->bf16, gamma folded (weights L3-cached, shared by blocks)
        const float* wdp = Wdn + (size_t)t * R * C + (size_t)(pw * 16 + lr) * C;
        bf16x8 a1[24];
        #pragma unroll
        for (int k = 0; k < 24; k++) {
            int col = k * 32 + lg * 8;
            float4 v0 = *reinterpret_cast<const float4*>(wdp + col);
            float4 v1 = *reinterpret_cast<const float4*>(wdp + col + 4);
            float4 g0 = *reinterpret_cast<const float4*>(gamma + col);
            float4 g1 = *reinterpret_cast<const float4*>(gamma + col + 4);
            bf16x8 a;
            a[0] = (short)f2bf(v0.x * g0.x); a[1] = (short)f2bf(v0.y * g0.y);
            a[2] = (short)f2bf(v0.z * g0.z); a[3] = (short)f2bf(v0.w * g0.w);
            a[4] = (short)f2bf(v1.x * g1.x); a[5] = (short)f2bf(v1.y * g1.y);
            a[6] = (short)f2bf(v1.z * g1.z); a[7] = (short)f2bf(v1.w * g1.w);
            a1[k] = a;
        }

        // u/w fold dots: lane handles row pw*16+lr over column group lg (192 cols)
        {
            const float* wrow = Wdn + ((size_t)t * R + (pw * 16 + lr)) * C + lg * 192;
            const float4* wr4 = (const float4*)wrow;
            const float4* g4  = (const float4*)(gamma + lg * 192);
            const float4* b4  = (const float4*)(beta  + lg * 192);
            float su = 0.f, sw = 0.f;
            #pragma unroll 8
            for (int j = 0; j < 48; j++) {
                float4 wv = wr4[j], gv = g4[j], bv = b4[j];
                su += wv.x*gv.x + wv.y*gv.y + wv.z*gv.z + wv.w*gv.w;
                sw += wv.x*bv.x + wv.y*bv.y + wv.z*bv.z + wv.w*bv.w;
            }
            su += __shfl_xor(su, 16); su += __shfl_xor(su, 32);
            sw += __shfl_xor(sw, 16); sw += __shfl_xor(sw, 32);
            if (lg == 0) { uws[pw][lr][0] = su; uws[pw][lr][1] = sw; }
        }

        __syncthreads();                                   // red[] + uws[] complete
        if (tid == 0) {
            float S = 0.f, Q = 0.f;
            #pragma unroll
            for (int wv = 0; wv < 8; wv++) { S += red[wv][0]; Q += red[wv][1]; }
            __hip_atomic_store(&partials[bid * 2],     S, __ATOMIC_RELEASE, __HIP_MEMORY_SCOPE_AGENT);
            __hip_atomic_store(&partials[bid * 2 + 1], Q, __ATOMIC_RELEASE, __HIP_MEMORY_SCOPE_AGENT);
        }
        cooperative_groups::this_grid().sync();

        // phase 2a: reduce this sample's 16 chunk-partials
        float s1 = 0.f, s2 = 0.f;
        if (lane < 16) {
            s1 = __hip_atomic_load(&partials[(b * 16 + lane) * 2],     __ATOMIC_ACQUIRE, __HIP_MEMORY_SCOPE_AGENT);
            s2 = __hip_atomic_load(&partials[(b * 16 + lane) * 2 + 1], __ATOMIC_ACQUIRE, __HIP_MEMORY_SCOPE_AGENT);
        }
        #pragma unroll
        for (int off = 8; off > 0; off >>= 1) {
            s1 += __shfl_xor(s1, off);
            s2 += __shfl_xor(s2, off);
        }
        s1 = __shfl(s1, 0); s2 = __shfl(s2, 0);
        float mean = s1 * (1.f / NPS);
        float var  = s2 * (1.f / NPS) - mean * mean;
        float rstd = rsqrtf(var + GN_EPS);
        float mb = rstd * mean;
        int r00 = lg * 4;
        float bias0 = uws[pw][r00+0][1] - mb * uws[pw][r00+0][0];
        float bias1 = uws[pw][r00+1][1] - mb * uws[pw][r00+1][0];
        float bias2 = uws[pw][r00+2][1] - mb * uws[pw][r00+2][0];
        float bias3 = uws[pw][r00+3][1] - mb * uws[pw][r00+3][0];

        STAGE(xsb, 0);
        STAGE(xsb + 49152, 1);

        for (int i = 0; i < 16; i++) {
            if (i == 15) asm volatile("s_waitcnt vmcnt(0)" ::: "memory");
            else         asm volatile("s_waitcnt vmcnt(12)" ::: "memory");
            __builtin_amdgcn_s_barrier();                  // #A: tile i ready (ALL waves)

            const char* xb = xsb + (i % 3) * 49152;
            f32x4 acc1a = {0.f, 0.f, 0.f, 0.f};
            f32x4 acc1b = {0.f, 0.f, 0.f, 0.f};
            #pragma unroll
            for (int k = 0; k < 24; k += 2) {
                #pragma unroll
                for (int kk = 0; kk < 2; kk++) {
                    int kc = k + kk;
                    int cb0 = (kc * 128 + lg * 32) ^ swz;
                    int cb1 = (kc * 128 + lg * 32 + 16) ^ swz;
                    f32x4 xv0 = *reinterpret_cast<const f32x4*>(xb + lr * 3072 + cb0);
                    f32x4 xv1 = *reinterpret_cast<const f32x4*>(xb + lr * 3072 + cb1);
                    bf16x8 bfrag;
                    bfrag[0] = (short)f2bf(xv0[0]); bfrag[1] = (short)f2bf(xv0[1]);
                    bfrag[2] = (short)f2bf(xv0[2]); bfrag[3] = (short)f2bf(xv0[3]);
                    bfrag[4] = (short)f2bf(xv1[0]); bfrag[5] = (short)f2bf(xv1[1]);
                    bfrag[6] = (short)f2bf(xv1[2]); bfrag[7] = (short)f2bf(xv1[3]);
                    if (kk == 0)
                        acc1a = __builtin_amdgcn_mfma_f32_16x16x32_bf16(a1[kc], bfrag, acc1a, 0, 0, 0);
                    else
                        acc1b = __builtin_amdgcn_mfma_f32_16x16x32_bf16(a1[kc], bfrag, acc1b, 0, 0, 0);
                }
            }
            float v0 = rstd * (acc1a[0] + acc1b[0]) + bias0;
            float v1 = rstd * (acc1a[1] + acc1b[1]) + bias1;
            float v2 = rstd * (acc1a[2] + acc1b[2]) + bias2;
            float v3 = rstd * (acc1a[3] + acc1b[3]) + bias3;
            ushort4 o;
            o.x = f2bf(0.5f * v0 * (1.f + erff(v0 * 0.70710678118f)));
            o.y = f2bf(0.5f * v1 * (1.f + erff(v1 * 0.70710678118f)));
            o.z = f2bf(0.5f * v2 * (1.f + erff(v2 * 0.70710678118f)));
            o.w = f2bf(0.5f * v3 * (1.f + erff(v3 * 0.70710678118f)));
            int hbyte = lr * 128 + ((pw * 32 + lg * 8) ^ swz);
            *reinterpret_cast<ushort4*>(hsb[i & 1] + hbyte) = o;

            asm volatile("s_waitcnt lgkmcnt(0)" ::: "memory");
            __builtin_amdgcn_s_barrier();                  // #B: h(i) published, x(i-1) reads done
            if (i + 2 < 16) STAGE(xsb + ((i + 2) % 3) * 49152, i + 2);
        }
    } else {
        // ======================= CONSUMER (waves 4-7) =======================
        int cw = wvid - 4;

        // phase 1b: a2 frags fp32->bf16 (Wu is [T][C][R])
        const float* wup = Wup + (size_t)t * C * R;
        bf16x8 a2[12][2];
        #pragma unroll
        for (int cb = 0; cb < 12; cb++) {
            #pragma unroll
            for (int ks = 0; ks < 2; ks++) {
                const float* src = wup + (size_t)(cw * 192 + cb * 16 + lr) * R + ks * 32 + lg * 8;
                float4 v0 = *reinterpret_cast<const float4*>(src);
                float4 v1 = *reinterpret_cast<const float4*>(src + 4);
                bf16x8 a;
                a[0] = (short)f2bf(v0.x); a[1] = (short)f2bf(v0.y);
                a[2] = (short)f2bf(v0.z); a[3] = (short)f2bf(v0.w);
                a[4] = (short)f2bf(v1.x); a[5] = (short)f2bf(v1.y);
                a[6] = (short)f2bf(v1.z); a[7] = (short)f2bf(v1.w);
                a2[cb][ks] = a;
            }
        }

        __syncthreads();                                   // pairs with producer
        cooperative_groups::this_grid().sync();

        for (int i = 0; i < 16; i++) {
            __builtin_amdgcn_s_barrier();                  // #A: tile i ready
            if (i > 0) {
                int j = i - 1;
                const char* xb = xsb + (j % 3) * 49152;
                bf16x8 b2[2];
                #pragma unroll
                for (int ks = 0; ks < 2; ks++) {
                    int byte = lr * 128 + ((ks * 64 + lg * 16) ^ swz);
                    b2[ks] = *reinterpret_cast<const bf16x8*>(hsb[j & 1] + byte);
                }
                size_t ro = (size_t)(j * 16 + lr) * C;
                #pragma unroll
                for (int cb = 0; cb < 12; cb++) {
                    f32x4 acc = {0.f, 0.f, 0.f, 0.f};
                    acc = __builtin_amdgcn_mfma_f32_16x16x32_bf16(a2[cb][0], b2[0], acc, 0, 0, 0);
                    acc = __builtin_amdgcn_mfma_f32_16x16x32_bf16(a2[cb][1], b2[1], acc, 0, 0, 0);
                    int c0 = cw * 192 + cb * 16 + lg * 4;
                    float4 xr = *reinterpret_cast<const float4*>(xb + lr * 3072 + ((c0 * 4) ^ swz));
                    f32x4 ov;
                    ov[0] = xr.x + sc * acc[0];
                    ov[1] = xr.y + sc * acc[1];
                    ov[2] = xr.z + sc * acc[2];
                    ov[3] = xr.w + sc * acc[3];
                    __builtin_nontemporal_store(ov, reinterpret_cast<f32x4*>(outp + ro + c0));
                }
            }
            __builtin_amdgcn_s_barrier();                  // #B
        }
        // tail: tile 15 (h(15) published at #B of iter 15; xsb[15%3=0] never re-staged)
        {
            int j = 15;
            const char* xb = xsb + (j % 3) * 49152;
            bf16x8 b2[2];
            #pragma unroll
            for (int ks = 0; ks < 2; ks++) {
                int byte = lr * 128 + ((ks * 64 + lg * 16) ^ swz);
                b2[ks] = *reinterpret_cast<const bf16x8*>(hsb[j & 1] + byte);
            }
            size_t ro = (size_t)(j * 16 + lr) * C;
            #pragma unroll
            for (int cb = 0; cb < 12; cb++) {
                f32x4 acc = {0.f, 0.f, 0.f, 0.f};
                acc = __builtin_amdgcn_mfma_f32_16x16x32_bf16(a2[cb][0], b2[0], acc, 0, 0, 0);
                acc = __builtin_amdgcn_mfma_f32_16x16x32_bf16(a2[cb][1], b2[1], acc, 0, 0, 0);
                int c0 = cw * 192 + cb * 16 + lg * 4;
                float4 xr = *reinterpret_cast<const float4*>(xb + lr * 3072 + ((c0 * 4) ^ swz));
                f32x4 ov;
                ov[0] = xr.x + sc * acc[0];
                ov[1] = xr.y + sc * acc[1];
                ov[2] = xr.z + sc * acc[2];
                ov[3] = xr.w + sc * acc[3];
                __builtin_nontemporal_store(ov, reinterpret_cast<f32x4*>(outp + ro + c0));
            }
        }
    }
#undef STAGE
}

extern "C" void kernel_launch(void* const* d_in, const int* in_sizes, int n_in,
                              void* d_out, int out_size, void* d_ws, size_t ws_size,
                              hipStream_t stream) {
    const float* x        = (const float*)d_in[0];
    const int*   task_ids = (const int*)d_in[1];
    const float* gamma    = (const float*)d_in[2];
    const float* beta     = (const float*)d_in[3];
    const float* W_down   = (const float*)d_in[4];
    const float* W_up     = (const float*)d_in[5];
    const float* scales   = (const float*)d_in[6];
    float* out = (float*)d_out;
    float* partials = (float*)d_ws;   // 256 blocks x 2 floats

    void* args[] = {(void*)&x, (void*)&task_ids, (void*)&gamma, (void*)&beta,
                    (void*)&W_down, (void*)&W_up, (void*)&scales,
                    (void*)&partials, (void*)&out};
    hipLaunchCooperativeKernel(reinterpret_cast<void*>(fused_all),
                               dim3(256), dim3(512), args, 0, stream);
}